// Round 1
// baseline (444.111 us; speedup 1.0000x reference)
//
#include <hip/hip_runtime.h>

constexpr int kB = 32;      // batch
constexpr int kA = 8400;    // anchors total (80*80 + 40*40 + 20*20)
constexpr int kG = 60;      // max GTs
constexpr int kC = 80;      // classes
constexpr int kK = 10;      // top-k

__device__ __forceinline__ float sigm(float x){ return 1.0f/(1.0f+expf(-x)); }

__device__ __forceinline__ float bce(float x, float t){
  // max(x,0) - x*t + log1p(exp(-|x|))
  return fmaxf(x, 0.0f) - x*t + log1pf(expf(-fabsf(x)));
}

struct AInfo { int x, y; float st; };
__device__ __forceinline__ AInfo ainfo(int a){
  AInfo r;
  if (a < 6400)      { r.x = a % 80;           r.y = a / 80;           r.st = 8.0f;  }
  else if (a < 8000) { int l = a-6400; r.x = l % 40; r.y = l / 40;     r.st = 16.0f; }
  else               { int l = a-8000; r.x = l % 20; r.y = l / 20;     r.st = 32.0f; }
  return r;
}

// feat value for (batch b, channel ch, anchor a); layout (B, 85, H, W), a = y*W+x per level
__device__ __forceinline__ float featv(const float* __restrict__ f8,
                                       const float* __restrict__ f16,
                                       const float* __restrict__ f32x,
                                       int b, int ch, int a){
  if (a < 6400) return f8 [(b*85 + ch)*6400 + a];
  if (a < 8000) return f16[(b*85 + ch)*1600 + (a - 6400)];
  return             f32x[(b*85 + ch)*400  + (a - 8000)];
}

// _pair_iou(gt, pred): area_a from gt, denominator (area_a + area_b - inter + 1e-16)
__device__ __forceinline__ float pair_iou(float4 g, float4 p){
  float tlx = fmaxf(g.x - g.z*0.5f, p.x - p.z*0.5f);
  float tly = fmaxf(g.y - g.w*0.5f, p.y - p.w*0.5f);
  float brx = fminf(g.x + g.z*0.5f, p.x + p.z*0.5f);
  float bry = fminf(g.y + g.w*0.5f, p.y + p.w*0.5f);
  float inter = (tlx < brx && tly < bry) ? (brx-tlx)*(bry-tly) : 0.0f;
  return inter / (g.z*g.w + p.z*p.w - inter + 1e-16f);
}

// Full SimOTA cost for (g, a) — shared by k_assign and conflict resolution in k_loss
// so rounding is bit-identical between the two.
__device__ __forceinline__ float cost_at(const float* __restrict__ f8,
                                         const float* __restrict__ f16,
                                         const float* __restrict__ f32x,
                                         int b, int a, float b0sum, float obj_sig, int fg_a,
                                         float4 bx, float4 gt, int cls){
  float iou = pair_iou(gt, bx);
  AInfo ai = ainfo(a);
  float cx = ((float)ai.x + 0.5f)*ai.st;
  float cy = ((float)ai.y + 0.5f)*ai.st;
  bool in_box = (cx > gt.x - 0.5f*gt.z) && (cx < gt.x + 0.5f*gt.z)
             && (cy > gt.y - 0.5f*gt.w) && (cy < gt.y + 0.5f*gt.w);
  bool in_ctr = (cx > gt.x - 2.5f*ai.st) && (cx < gt.x + 2.5f*ai.st)
             && (cy > gt.y - 2.5f*ai.st) && (cy < gt.y + 2.5f*ai.st);
  float cl = featv(f8, f16, f32x, b, 5 + cls, a);
  float p = sqrtf(sigm(cl) * obj_sig);
  p = fminf(fmaxf(p, 1e-7f), 1.0f - 1e-7f);
  float diff = -logf(p) + logf(1.0f - p);      // bce1 - bce0 at class cls
  float c = b0sum + diff;
  c += 3.0f * (-logf(iou + 1e-8f));
  c += (in_box && in_ctr) ? 0.0f : 100000.0f;
  c += fg_a ? 0.0f : 1000000000.0f;
  return c;
}

__global__ void k_zero(float* acc){ if (threadIdx.x < 4) acc[threadIdx.x] = 0.0f; }

__global__ __launch_bounds__(256) void k_decode(
    const float* __restrict__ f8, const float* __restrict__ f16, const float* __restrict__ f32x,
    const float* __restrict__ gtb, const int* __restrict__ ngts,
    float* __restrict__ boxes, float* __restrict__ objl, float* __restrict__ b0s,
    int* __restrict__ fg, int* __restrict__ cnt, int* __restrict__ mtch){
  int b = blockIdx.y;
  int a = blockIdx.x*256 + threadIdx.x;
  __shared__ float4 sg[kG];
  if (threadIdx.x < kG) sg[threadIdx.x] = ((const float4*)gtb)[b*kG + threadIdx.x];
  __syncthreads();
  if (a >= kA) return;
  int ng = ngts[b];
  AInfo ai = ainfo(a);
  float t0 = featv(f8,f16,f32x,b,0,a);
  float t1 = featv(f8,f16,f32x,b,1,a);
  float t2 = featv(f8,f16,f32x,b,2,a);
  float t3 = featv(f8,f16,f32x,b,3,a);
  float ob = featv(f8,f16,f32x,b,4,a);
  float4 bx;
  bx.x = (t0 + (float)ai.x) * ai.st;
  bx.y = (t1 + (float)ai.y) * ai.st;
  bx.z = expf(t2) * ai.st;
  bx.w = expf(t3) * ai.st;
  int idx = b*kA + a;
  ((float4*)boxes)[idx] = bx;
  objl[idx] = ob;
  float obs = sigm(ob);
  float s = 0.0f;
  for (int c = 0; c < kC; ++c){
    float cl = featv(f8,f16,f32x,b,5+c,a);
    float p = sqrtf(sigm(cl)*obs);
    p = fminf(fmaxf(p, 1e-7f), 1.0f - 1e-7f);
    s += -logf(1.0f - p);           // bce0
  }
  b0s[idx] = s;
  float cx = ((float)ai.x + 0.5f)*ai.st;
  float cy = ((float)ai.y + 0.5f)*ai.st;
  int f = 0;
  for (int g = 0; g < ng; ++g){
    float4 gt = sg[g];
    bool in_box = (cx > gt.x - 0.5f*gt.z) && (cx < gt.x + 0.5f*gt.z)
               && (cy > gt.y - 0.5f*gt.w) && (cy < gt.y + 0.5f*gt.w);
    bool in_ctr = (cx > gt.x - 2.5f*ai.st) && (cx < gt.x + 2.5f*ai.st)
               && (cy > gt.y - 2.5f*ai.st) && (cy < gt.y + 2.5f*ai.st);
    if (in_box || in_ctr){ f = 1; break; }
  }
  fg[idx] = f;
  cnt[idx] = 0;
  mtch[idx] = 0x7fffffff;
}

__global__ __launch_bounds__(256) void k_assign(
    const float* __restrict__ f8, const float* __restrict__ f16, const float* __restrict__ f32x,
    const float* __restrict__ gtb, const int* __restrict__ gtc, const int* __restrict__ ngts,
    const float* __restrict__ boxes, const float* __restrict__ objl, const float* __restrict__ b0s,
    const int* __restrict__ fg, int* __restrict__ cnt, int* __restrict__ mtch){
  int b = blockIdx.x / kG;
  int g = blockIdx.x % kG;
  if (g >= ngts[b]) return;     // vmask: invalid rows contribute nothing
  int tid = threadIdx.x;
  float4 gt = ((const float4*)gtb)[b*kG + g];
  int cls = gtc[b*kG + g];
  __shared__ float sv[kA];      // 33.6 KB row buffer
  __shared__ float rv[256];
  __shared__ int   ri[256];
  __shared__ int   spos[kK];
  __shared__ int   sdynk;
  const float4* bx4 = (const float4*)boxes;

  // ---- pass 1: iou * fg ----
  for (int a = tid; a < kA; a += 256){
    float iou = pair_iou(gt, bx4[b*kA + a]);
    sv[a] = fg[b*kA + a] ? iou : 0.0f;
  }
  __syncthreads();
  float ksum = 0.0f;            // only tid 0's copy is used
  for (int k = 0; k < kK; ++k){
    float bv = -1.0f; int bi = 0x7fffffff;
    for (int a = tid; a < kA; a += 256){
      float v = sv[a];
      if (v > bv || (v == bv && a < bi)){ bv = v; bi = a; }
    }
    rv[tid] = bv; ri[tid] = bi;
    __syncthreads();
    for (int s = 128; s > 0; s >>= 1){
      if (tid < s){
        if (rv[tid+s] > rv[tid] || (rv[tid+s] == rv[tid] && ri[tid+s] < ri[tid])){
          rv[tid] = rv[tid+s]; ri[tid] = ri[tid+s];
        }
      }
      __syncthreads();
    }
    if (tid == 0){ ksum += rv[0]; sv[ri[0]] = -1.0f; }
    __syncthreads();
  }
  if (tid == 0) sdynk = max((int)ksum, 1);   // truncation matches astype(int32)

  // ---- pass 2: cost ----
  for (int a = tid; a < kA; a += 256){
    int idx = b*kA + a;
    float obs = sigm(objl[idx]);
    sv[a] = cost_at(f8,f16,f32x,b,a,b0s[idx],obs,fg[idx],bx4[idx],gt,cls);
  }
  __syncthreads();
  for (int k = 0; k < kK; ++k){
    float bv = 3.0e38f; int bi = 0x7fffffff;
    for (int a = tid; a < kA; a += 256){
      float v = sv[a];
      if (v < bv || (v == bv && a < bi)){ bv = v; bi = a; }
    }
    rv[tid] = bv; ri[tid] = bi;
    __syncthreads();
    for (int s = 128; s > 0; s >>= 1){
      if (tid < s){
        if (rv[tid+s] < rv[tid] || (rv[tid+s] == rv[tid] && ri[tid+s] < ri[tid])){
          rv[tid] = rv[tid+s]; ri[tid] = ri[tid+s];
        }
      }
      __syncthreads();
    }
    if (tid == 0){ spos[k] = ri[0]; sv[ri[0]] = 3.0e38f; }
    __syncthreads();
  }
  if (tid < kK && tid < sdynk){
    int a = spos[tid];
    atomicAdd(&cnt[b*kA + a], 1);
    atomicMin(&mtch[b*kA + a], g);
  }
}

__global__ __launch_bounds__(256) void k_loss(
    const float* __restrict__ f8, const float* __restrict__ f16, const float* __restrict__ f32x,
    const float* __restrict__ gtb, const int* __restrict__ gtc, const int* __restrict__ ngts,
    const float* __restrict__ boxes, const float* __restrict__ objl, const float* __restrict__ b0s,
    const int* __restrict__ fg, const int* __restrict__ cnt, const int* __restrict__ mtch,
    float* __restrict__ acc){
  int b = blockIdx.y;
  int a = blockIdx.x*256 + threadIdx.x;
  int tid = threadIdx.x;
  __shared__ float4 sg[kG];
  __shared__ int scls[kG];
  if (tid < kG){ sg[tid] = ((const float4*)gtb)[b*kG + tid]; scls[tid] = gtc[b*kG + tid]; }
  __syncthreads();
  float li = 0.0f, lo = 0.0f, lc = 0.0f, nf = 0.0f;
  if (a < kA){
    int idx = b*kA + a;
    float ob = objl[idx];
    int c = cnt[idx];
    float4 bx = ((const float4*)boxes)[idx];
    float fgf = 0.0f; int mg = 0; float piou = 0.0f;
    if (c == 1){
      mg = mtch[idx]; fgf = 1.0f; piou = pair_iou(sg[mg], bx);
    } else if (c > 1){
      // conflict: argmin over valid GTs (invalid carry +1e9, can never win)
      int ng = ngts[b];
      float b0 = b0s[idx];
      float obs = sigm(ob);
      int fga = fg[idx];
      float bestc = 3.0e38f; int bg = 0;
      for (int g = 0; g < ng; ++g){
        float cst = cost_at(f8,f16,f32x,b,a,b0,obs,fga,bx,sg[g],scls[g]);
        if (cst < bestc){ bestc = cst; bg = g; }   // strict < : first min, jnp.argmin
      }
      mg = bg; fgf = 1.0f; piou = pair_iou(sg[bg], bx);
    }
    lo = bce(ob, fgf*0.9f);
    if (fgf > 0.0f){
      nf = 1.0f;
      float4 r = sg[mg];
      // _iou_loss: union = areas - inter, then /(union + 1e-16)
      float tlx = fmaxf(bx.x - bx.z*0.5f, r.x - r.z*0.5f);
      float tly = fmaxf(bx.y - bx.w*0.5f, r.y - r.w*0.5f);
      float brx = fminf(bx.x + bx.z*0.5f, r.x + r.z*0.5f);
      float bry = fminf(bx.y + bx.w*0.5f, r.y + r.w*0.5f);
      float inter = (tlx < brx && tly < bry) ? (brx-tlx)*(bry-tly) : 0.0f;
      float un = bx.z*bx.w + r.z*r.w - inter;
      float iou = inter / (un + 1e-16f);
      li = 1.0f - iou*iou;
      int tc = scls[mg];
      for (int cc = 0; cc < kC; ++cc){
        float cl = featv(f8,f16,f32x,b,5+cc,a);
        float t = (cc == tc) ? piou : 0.0f;
        lc += bce(cl, t);
      }
    }
  }
  __shared__ float4 red[256];
  red[tid] = make_float4(li, lo, lc, nf);
  __syncthreads();
  for (int s = 128; s > 0; s >>= 1){
    if (tid < s){
      float4 o = red[tid+s];
      red[tid].x += o.x; red[tid].y += o.y; red[tid].z += o.z; red[tid].w += o.w;
    }
    __syncthreads();
  }
  if (tid == 0){
    atomicAdd(&acc[0], red[0].x);
    atomicAdd(&acc[1], red[0].y);
    atomicAdd(&acc[2], red[0].z);
    atomicAdd(&acc[3], red[0].w);
  }
}

__global__ void k_final(const float* __restrict__ acc, float* __restrict__ out){
  out[0] = (5.0f*acc[0] + acc[1] + acc[2]) / fmaxf(acc[3], 1.0f);
}

extern "C" void kernel_launch(void* const* d_in, const int* in_sizes, int n_in,
                              void* d_out, int out_size, void* d_ws, size_t ws_size,
                              hipStream_t stream) {
  (void)in_sizes; (void)n_in; (void)out_size; (void)ws_size;
  const float* f8   = (const float*)d_in[0];
  const float* f16  = (const float*)d_in[1];
  const float* f32x = (const float*)d_in[2];
  const float* gtb  = (const float*)d_in[3];
  const int*   gtc  = (const int*)d_in[4];
  const int*   ngts = (const int*)d_in[5];
  float* out = (float*)d_out;

  float* ws    = (float*)d_ws;
  float* boxes = ws;                              // B*A*4
  float* objl  = boxes + (size_t)kB*kA*4;         // B*A
  float* b0s   = objl  + (size_t)kB*kA;           // B*A
  int*   fg    = (int*)(b0s + (size_t)kB*kA);     // B*A
  int*   cnt   = fg  + (size_t)kB*kA;             // B*A
  int*   mtch  = cnt + (size_t)kB*kA;             // B*A
  float* acc   = (float*)(mtch + (size_t)kB*kA);  // 4

  dim3 gBA((kA + 255)/256, kB);
  k_zero<<<dim3(1), dim3(64), 0, stream>>>(acc);
  k_decode<<<gBA, dim3(256), 0, stream>>>(f8,f16,f32x,gtb,ngts,boxes,objl,b0s,fg,cnt,mtch);
  k_assign<<<dim3(kB*kG), dim3(256), 0, stream>>>(f8,f16,f32x,gtb,gtc,ngts,boxes,objl,b0s,fg,cnt,mtch);
  k_loss<<<gBA, dim3(256), 0, stream>>>(f8,f16,f32x,gtb,gtc,ngts,boxes,objl,b0s,fg,cnt,mtch,acc);
  k_final<<<dim3(1), dim3(1), 0, stream>>>(acc, out);
}